// Round 9
// baseline (211.285 us; speedup 1.0000x reference)
//
#include <hip/hip_runtime.h>
#include <math.h>

#define BB 512       // batch rows (M)
#define DD 512       // depth (K)
#define CC 100000    // classes (N)
#define MARGIN2 0.5f
#define PI_F 3.14159265358979323846f

#define BM 256
#define BN 128
#define BK 64
#define KSTEPS (DD / BK)     // 8
#define NPAN 782             // ceil(100000/128), last panel 32 cols
#define GRID (2 * NPAN)      // 1564 blocks

typedef __bf16 bf16x8 __attribute__((ext_vector_type(8)));
typedef float f32x4 __attribute__((ext_vector_type(4)));

static __device__ __forceinline__ unsigned short f2bf(float f) {
    union { float f; unsigned u; } v; v.f = f;
    unsigned r = v.u + 0x7FFFu + ((v.u >> 16) & 1u);   // round-to-nearest-even
    return (unsigned short)(r >> 16);
}

// swizzled LDS byte offset for row-major [row][64 x bf16] tiles (row stride 128B)
static __device__ __forceinline__ int swz(int row, int kbyte) {
    return row * 128 + (kbyte ^ ((row & 7) << 4));
}

// ---------------- K1: row-normalize x -> bf16 (plain row-major) ----------------
__global__ __launch_bounds__(256) void k_norm_x(const float* __restrict__ x,
                                                unsigned short* __restrict__ xnb) {
    const int lane = threadIdx.x & 63;
    const int row  = blockIdx.x * 4 + (threadIdx.x >> 6);
    const float* xr = x + (size_t)row * DD;
    float4 v0 = *(const float4*)(xr + lane * 4);
    float4 v1 = *(const float4*)(xr + lane * 4 + 256);
    float s = v0.x*v0.x + v0.y*v0.y + v0.z*v0.z + v0.w*v0.w
            + v1.x*v1.x + v1.y*v1.y + v1.z*v1.z + v1.w*v1.w;
    #pragma unroll
    for (int m = 32; m; m >>= 1) s += __shfl_xor(s, m, 64);
    float rs = rsqrtf(fmaxf(s, 1e-12f));
    ushort4 o0, o1;
    o0.x = f2bf(v0.x * rs); o0.y = f2bf(v0.y * rs);
    o0.z = f2bf(v0.z * rs); o0.w = f2bf(v0.w * rs);
    o1.x = f2bf(v1.x * rs); o1.y = f2bf(v1.y * rs);
    o1.z = f2bf(v1.z * rs); o1.w = f2bf(v1.w * rs);
    *(ushort4*)(xnb + (size_t)row * DD + lane * 4)       = o0;
    *(ushort4*)(xnb + (size_t)row * DD + lane * 4 + 256) = o1;
}

// ---------------- K2: bf16 MFMA GEMM, A direct-from-L2, lean-barrier pipeline ----
// LDS: bufB = 2 x 16KB dbuf only ([n][64k] bf16 swizzled) + rn 512B = 33KB
//      -> with VGPR<=128 (launch_bounds 512,4): 2 blocks/CU, 4 waves/SIMD.
// A (xn, 512KB, L2-resident) is read straight into MFMA regs: 16B/lane,
// 64B-granular, 128B-aligned rows - no staging, no vmcnt at barriers.
// Per-iter issue order (pinned; vmcnt is an in-order FIFO, so A-consumption
// must not sit behind fresh B loads):
//   [af 8 loads] [PACK B(t+1) (counted vmcnt drains only old freg)]
//   [ds_write pk -> B(t+1) buf early] [LOAD freg = B(t+2)]
//   [COMPUTE: af use waits vmcnt(16), leaves freg in flight]
//   [lgkmcnt(0); s_barrier]  - no vmcnt drain ever in the main loop (T4).
#define LDSZ (32768 + 512)

__global__ __launch_bounds__(512, 4) void k_gemm(const unsigned short* __restrict__ xnb,
                                                 const float* __restrict__ W,
                                                 float* __restrict__ out) {
    __shared__ __align__(16) unsigned char LDS[LDSZ];
    unsigned char* bufB = LDS;                  // 2 x 16384
    float* rn = (float*)(LDS + 32768);

    const int tid = threadIdx.x;
    const int bid = blockIdx.x;

    // bijective XCD swizzle (1564 = 8*195 + 4): mb-pairs of a W panel share one XCD's L2
    const int xcd = bid & 7;
    const int jj  = bid >> 3;
    const int v   = (xcd < 4) ? (xcd * 196 + jj) : (784 + (xcd - 4) * 195 + jj);
    const int mb  = v & 1;
    const int nb  = v >> 1;
    const int M0 = mb * BM;
    const int N0 = nb * BN;

    const int lane = tid & 63;
    const int wid  = tid >> 6;     // 0..7
    const int wm = wid >> 1;       // 0..3 -> 64 rows each
    const int wn = wid & 1;        // 0..1 -> 64 cols each
    const int lr = lane & 15;
    const int lg = lane >> 4;

    // A fragment pointers: row = M0 + wm*64 + mf*16 + lr, k-offset lg*8.
    // All per-(t,ks) deltas are compile-time (<=960 elems) -> fold into offset field.
    const unsigned short* aptr0 = xnb + (size_t)(M0 + wm * 64 +  0 + lr) * DD + lg * 8;
    const unsigned short* aptr1 = xnb + (size_t)(M0 + wm * 64 + 16 + lr) * DD + lg * 8;
    const unsigned short* aptr2 = xnb + (size_t)(M0 + wm * 64 + 32 + lr) * DD + lg * 8;
    const unsigned short* aptr3 = xnb + (size_t)(M0 + wm * 64 + 48 + lr) * DD + lg * 8;

    float    freg[4][4];           // B(t+2) in flight (16 f32)
    unsigned pk[8];                // B(t+1) packed bf16 pairs
    float    bsq[4] = {0.f, 0.f, 0.f, 0.f};
    bf16x8   af[8];                // A frags for current tile (ks0: 0..3, ks1: 4..7)

#define LOAD_B(T) do {                                                         \
    _Pragma("unroll")                                                          \
    for (int i = 0; i < 4; ++i) {                                              \
        const int s_ = tid + i * 512;                                          \
        const int n_ = s_ & 127;                                               \
        const int kq_ = s_ >> 7;                                               \
        int col_ = N0 + n_; col_ = col_ < CC ? col_ : CC - 1;                  \
        const float* p = W + (size_t)kq_ * 4 * CC + col_ + (size_t)(T) * (BK * CC); \
        freg[i][0] = p[0];      freg[i][1] = p[CC];                            \
        freg[i][2] = p[2 * CC]; freg[i][3] = p[3 * CC];                        \
    } } while (0)

#define PACK() do {                                                            \
    _Pragma("unroll")                                                          \
    for (int i = 0; i < 4; ++i) {                                              \
        bsq[i] += freg[i][0] * freg[i][0] + freg[i][1] * freg[i][1]            \
                + freg[i][2] * freg[i][2] + freg[i][3] * freg[i][3];           \
        asm("v_cvt_pk_bf16_f32 %0, %1, %2" : "=v"(pk[2*i])   : "v"(freg[i][0]), "v"(freg[i][1])); \
        asm("v_cvt_pk_bf16_f32 %0, %1, %2" : "=v"(pk[2*i+1]) : "v"(freg[i][2]), "v"(freg[i][3])); \
    } } while (0)

#define WRITE_PK(T) do {                                                       \
    unsigned char* dst = bufB + ((T) & 1) * 16384;                             \
    _Pragma("unroll")                                                          \
    for (int i = 0; i < 4; ++i) {                                              \
        const int s_ = tid + i * 512;                                          \
        const int n_ = s_ & 127;                                               \
        const int kq_ = s_ >> 7;                                               \
        uint2 w; w.x = pk[2*i]; w.y = pk[2*i+1];                               \
        *(uint2*)(dst + n_ * 128 + ((kq_ * 8) ^ ((n_ & 7) << 4))) = w;         \
    } } while (0)

#define LOAD_AF(T) do {                                                        \
    af[0] = *(const bf16x8*)(aptr0 + (T) * 64);                                \
    af[1] = *(const bf16x8*)(aptr1 + (T) * 64);                                \
    af[2] = *(const bf16x8*)(aptr2 + (T) * 64);                                \
    af[3] = *(const bf16x8*)(aptr3 + (T) * 64);                                \
    af[4] = *(const bf16x8*)(aptr0 + (T) * 64 + 32);                           \
    af[5] = *(const bf16x8*)(aptr1 + (T) * 64 + 32);                           \
    af[6] = *(const bf16x8*)(aptr2 + (T) * 64 + 32);                           \
    af[7] = *(const bf16x8*)(aptr3 + (T) * 64 + 32);                           \
    } while (0)

#define COMPUTE(T) do {                                                        \
    const unsigned char* B_cur = bufB + ((T) & 1) * 16384;                     \
    _Pragma("unroll")                                                          \
    for (int ks = 0; ks < 2; ++ks) {                                           \
        _Pragma("unroll")                                                      \
        for (int nf = 0; nf < 4; ++nf) {                                       \
            bf16x8 bfr = *(const bf16x8*)(B_cur + swz(wn * 64 + nf * 16 + lr, ks * 64 + lg * 16)); \
            _Pragma("unroll")                                                  \
            for (int mf = 0; mf < 4; ++mf)                                     \
                acc[mf][nf] = __builtin_amdgcn_mfma_f32_16x16x32_bf16(         \
                    bfr, af[ks * 4 + mf], acc[mf][nf], 0, 0, 0);               \
        }                                                                      \
    } } while (0)

#define KBODY(T) do {                                                          \
    LOAD_AF(T);                                /* oldest in vmcnt FIFO */      \
    __builtin_amdgcn_sched_barrier(0);                                         \
    if ((T) + 1 < KSTEPS) { PACK(); WRITE_PK((T) + 1); }                       \
    __builtin_amdgcn_sched_barrier(0);                                         \
    if ((T) + 2 < KSTEPS) LOAD_B((T) + 2);     /* newest - stays in flight */  \
    __builtin_amdgcn_sched_barrier(0);                                         \
    COMPUTE(T);                                                                \
    if ((T) + 1 < KSTEPS) {                                                    \
        asm volatile("s_waitcnt lgkmcnt(0)" ::: "memory");                     \
        __builtin_amdgcn_sched_barrier(0);                                     \
        __builtin_amdgcn_s_barrier();                                          \
        __builtin_amdgcn_sched_barrier(0);                                     \
    } } while (0)

    f32x4 acc[4][4];
    #pragma unroll
    for (int mf = 0; mf < 4; ++mf)
        #pragma unroll
        for (int nf = 0; nf < 4; ++nf)
            acc[mf][nf] = (f32x4)0.f;

    // ---- prologue: B(0) staged to buf0; B(1) left in flight across the barrier ----
    LOAD_B(0);
    PACK();
    WRITE_PK(0);
    LOAD_B(1);
    asm volatile("s_waitcnt lgkmcnt(0)" ::: "memory");
    __builtin_amdgcn_sched_barrier(0);
    __builtin_amdgcn_s_barrier();
    __builtin_amdgcn_sched_barrier(0);

    KBODY(0); KBODY(1); KBODY(2); KBODY(3);
    KBODY(4); KBODY(5); KBODY(6); KBODY(7);

    // ---- deterministic column-norm reduction (reuse bufB) ----
    __syncthreads();
    float* part = (float*)bufB;                // [16][128] floats = 8KB
    #pragma unroll
    for (int i = 0; i < 4; ++i)
        part[tid + i * 512] = bsq[i];          // slot = kq*128+n, unique owner
    __syncthreads();
    if (tid < BN) {
        float s = 0.f;
        #pragma unroll
        for (int k = 0; k < 16; ++k)
            s += part[k * BN + tid];           // fixed order -> deterministic
        rn[tid] = rsqrtf(fmaxf(s, 1e-12f));
    }
    __syncthreads();

    // ---- epilogue: LDS-staged -> 512B-aligned full-sector non-temporal stores ----
    float* stag = (float*)bufB;                // 32 rows x 132 floats = 16.9KB
    #pragma unroll
    for (int rd = 0; rd < 8; ++rd) {
        if (wm == (rd >> 1)) {
            #pragma unroll
            for (int f = 0; f < 2; ++f) {
                const int mf = (rd & 1) * 2 + f;
                const int ml = f * 16 + lr;
                #pragma unroll
                for (int nf = 0; nf < 4; ++nf) {
                    const int nl = wn * 64 + nf * 16 + lg * 4;
                    const f32x4 rn4 = *(const f32x4*)(rn + nl);
                    f32x4 o;
                    #pragma unroll
                    for (int r = 0; r < 4; ++r)
                        o[r] = acc[mf][nf][r] * rn4[r];
                    *(f32x4*)(stag + ml * 132 + nl) = o;
                }
            }
        }
        __syncthreads();
        #pragma unroll
        for (int j = tid; j < 1024; j += 512) {
            const int m = j >> 5;
            const int n = (j & 31) * 4;
            if (N0 + n + 4 <= CC) {
                f32x4 o = *(const f32x4*)(stag + m * 132 + n);
                __builtin_nontemporal_store(o,
                    (f32x4*)(out + (size_t)(M0 + rd * 32 + m) * CC + N0 + n));
            }
        }
        __syncthreads();
    }
}

// ---------------- K3: margin fixup at label positions ----------------
__global__ __launch_bounds__(512) void k_fix(const int* __restrict__ lab,
                                             float* __restrict__ out) {
    const int b = threadIdx.x;
    const int c = lab[b];
    const size_t idx = (size_t)b * CC + c;
    float t = out[idx];
    t = fminf(fmaxf(t, -1.f), 1.f);
    float th = acosf(t) + MARGIN2;
    th = fminf(th, PI_F);              // min(t, t + (pi - stopgrad(t))) value-wise
    out[idx] = cosf(th);               // M3 == 0: no additive term
}

extern "C" void kernel_launch(void* const* d_in, const int* in_sizes, int n_in,
                              void* d_out, int out_size, void* d_ws, size_t ws_size,
                              hipStream_t stream) {
    const float* x   = (const float*)d_in[0];
    const float* W   = (const float*)d_in[1];
    const int*   lab = (const int*)d_in[2];
    float* out = (float*)d_out;

    unsigned short* xnb = (unsigned short*)d_ws;   // 512*512*2 = 512 KB scratch

    k_norm_x<<<dim3(BB / 4), dim3(256), 0, stream>>>(x, xnb);
    k_gemm<<<dim3(GRID), dim3(512), 0, stream>>>(xnb, W, out);
    k_fix<<<dim3(1), dim3(512), 0, stream>>>(lab, out);
}

// Round 10
// 165.028 us; speedup vs baseline: 1.2803x; 1.2803x over previous
//
#include <hip/hip_runtime.h>
#include <math.h>

#define BB 512       // batch rows (M)
#define DD 512       // depth (K)
#define CC 100000    // classes (N)
#define MARGIN2 0.5f
#define PI_F 3.14159265358979323846f

#define BM 256
#define BN 128
#define BK 64
#define KSTEPS (DD / BK)     // 8
#define NPAN 782             // ceil(100000/128), last panel 32 cols
#define GRID (2 * NPAN)      // 1564 blocks

typedef __bf16 bf16x8 __attribute__((ext_vector_type(8)));
typedef float f32x4 __attribute__((ext_vector_type(4)));

static __device__ __forceinline__ unsigned short f2bf(float f) {
    union { float f; unsigned u; } v; v.f = f;
    unsigned r = v.u + 0x7FFFu + ((v.u >> 16) & 1u);   // round-to-nearest-even
    return (unsigned short)(r >> 16);
}

// swizzled LDS byte offset for row-major [row][64 x bf16] tiles (row stride 128B)
static __device__ __forceinline__ int swz(int row, int kbyte) {
    return row * 128 + (kbyte ^ ((row & 7) << 4));
}

// ---------------- K1: row-normalize x -> bf16 (plain row-major) ----------------
__global__ __launch_bounds__(256) void k_norm_x(const float* __restrict__ x,
                                                unsigned short* __restrict__ xnb) {
    const int lane = threadIdx.x & 63;
    const int row  = blockIdx.x * 4 + (threadIdx.x >> 6);
    const float* xr = x + (size_t)row * DD;
    float4 v0 = *(const float4*)(xr + lane * 4);
    float4 v1 = *(const float4*)(xr + lane * 4 + 256);
    float s = v0.x*v0.x + v0.y*v0.y + v0.z*v0.z + v0.w*v0.w
            + v1.x*v1.x + v1.y*v1.y + v1.z*v1.z + v1.w*v1.w;
    #pragma unroll
    for (int m = 32; m; m >>= 1) s += __shfl_xor(s, m, 64);
    float rs = rsqrtf(fmaxf(s, 1e-12f));
    ushort4 o0, o1;
    o0.x = f2bf(v0.x * rs); o0.y = f2bf(v0.y * rs);
    o0.z = f2bf(v0.z * rs); o0.w = f2bf(v0.w * rs);
    o1.x = f2bf(v1.x * rs); o1.y = f2bf(v1.y * rs);
    o1.z = f2bf(v1.z * rs); o1.w = f2bf(v1.w * rs);
    *(ushort4*)(xnb + (size_t)row * DD + lane * 4)       = o0;
    *(ushort4*)(xnb + (size_t)row * DD + lane * 4 + 256) = o1;
}

// ---------------- K2: bf16 MFMA GEMM, A-direct-from-L2, depth-3 counted pipeline ----
// LDS: bufB = 2 x 16KB dbuf only + rn 512B = 33KB. launch_bounds(512,2) -> 256-reg
// cap: acc 64 + af 2x32 + freg 3x16 + pk 8 + addr ~= 215, NO SPILL (R9 lesson).
// Per-iter (exact counted vmcnt, all compile-time; never vmcnt(0) until tail):
//   W1: vmcnt(24) drains only B(t+1)  [leaves af(t):8 + B(t+2):16]
//   PACK B(t+1) + ds_write -> buf((t+1)&1)
//   issue af(t+1):8, B(t+3):16        [48 in flight <= 63]
//   W4: vmcnt(40) drains only af(t)
//   COMPUTE(t) from af regs + bufB((t&1))
//   lgkmcnt(0); s_barrier             [no vmcnt at barrier - A never stages]
#define LDSZ (32768 + 512)

__global__ __launch_bounds__(512, 2) void k_gemm(const unsigned short* __restrict__ xnb,
                                                 const float* __restrict__ W,
                                                 float* __restrict__ out) {
    __shared__ __align__(16) unsigned char LDS[LDSZ];
    unsigned char* bufB = LDS;                  // 2 x 16384
    float* rn = (float*)(LDS + 32768);

    const int tid = threadIdx.x;
    const int bid = blockIdx.x;

    // bijective XCD swizzle (1564 = 8*195 + 4): mb-pairs of a W panel share one XCD's L2
    const int xcd = bid & 7;
    const int jj  = bid >> 3;
    const int v   = (xcd < 4) ? (xcd * 196 + jj) : (784 + (xcd - 4) * 195 + jj);
    const int mb  = v & 1;
    const int nb  = v >> 1;
    const int M0 = mb * BM;
    const int N0 = nb * BN;

    const int lane = tid & 63;
    const int wid  = tid >> 6;     // 0..7
    const int wm = wid >> 1;       // 0..3 -> 64 rows each
    const int wn = wid & 1;        // 0..1 -> 64 cols each
    const int lr = lane & 15;
    const int lg = lane >> 4;

    // A fragment pointers: row = M0 + wm*64 + mf*16 + lr, k byte offset lg*16.
    // Per-(t,ks) byte deltas t*128 + ks*64 <= 960 fit the global-load offset field.
    const unsigned short* aptr0 = xnb + (size_t)(M0 + wm * 64 +  0 + lr) * DD + lg * 8;
    const unsigned short* aptr1 = xnb + (size_t)(M0 + wm * 64 + 16 + lr) * DD + lg * 8;
    const unsigned short* aptr2 = xnb + (size_t)(M0 + wm * 64 + 32 + lr) * DD + lg * 8;
    const unsigned short* aptr3 = xnb + (size_t)(M0 + wm * 64 + 48 + lr) * DD + lg * 8;

    float    f0[4][4], f1[4][4], f2[4][4];   // B in flight, 3-deep rotation
    bf16x8   afA[8], afB[8];                 // A frags, 2-deep rotation
    unsigned pk[8];
    float    bsq[4] = {0.f, 0.f, 0.f, 0.f};

#define WAITV_(N) asm volatile("s_waitcnt vmcnt(" #N ")" ::: "memory")
#define WAITV(N) WAITV_(N)
#define SB() __builtin_amdgcn_sched_barrier(0)

#define LOAD_B(FR, T) do {                                                     \
    _Pragma("unroll")                                                          \
    for (int i = 0; i < 4; ++i) {                                              \
        const int s_ = tid + i * 512;                                          \
        const int n_ = s_ & 127;                                               \
        const int kq_ = s_ >> 7;                                               \
        int col_ = N0 + n_; col_ = col_ < CC ? col_ : CC - 1;                  \
        const float* p = W + (size_t)kq_ * 4 * CC + col_ + (size_t)(T) * (BK * CC); \
        FR[i][0] = p[0];      FR[i][1] = p[CC];                                \
        FR[i][2] = p[2 * CC]; FR[i][3] = p[3 * CC];                            \
    } } while (0)

#define PACK(FR) do {                                                          \
    _Pragma("unroll")                                                          \
    for (int i = 0; i < 4; ++i) {                                              \
        bsq[i] += FR[i][0] * FR[i][0] + FR[i][1] * FR[i][1]                    \
                + FR[i][2] * FR[i][2] + FR[i][3] * FR[i][3];                   \
        asm("v_cvt_pk_bf16_f32 %0, %1, %2" : "=v"(pk[2*i])   : "v"(FR[i][0]), "v"(FR[i][1])); \
        asm("v_cvt_pk_bf16_f32 %0, %1, %2" : "=v"(pk[2*i+1]) : "v"(FR[i][2]), "v"(FR[i][3])); \
    } } while (0)

#define WRITE_PK(T) do {                                                       \
    unsigned char* dst = bufB + ((T) & 1) * 16384;                             \
    _Pragma("unroll")                                                          \
    for (int i = 0; i < 4; ++i) {                                              \
        const int s_ = tid + i * 512;                                          \
        const int n_ = s_ & 127;                                               \
        const int kq_ = s_ >> 7;                                               \
        uint2 w; w.x = pk[2*i]; w.y = pk[2*i+1];                               \
        *(uint2*)(dst + n_ * 128 + ((kq_ * 8) ^ ((n_ & 7) << 4))) = w;         \
    } } while (0)

#define LOAD_AF(AF, T) do {                                                    \
    AF[0] = *(const bf16x8*)(aptr0 + (T) * 64);                                \
    AF[1] = *(const bf16x8*)(aptr1 + (T) * 64);                                \
    AF[2] = *(const bf16x8*)(aptr2 + (T) * 64);                                \
    AF[3] = *(const bf16x8*)(aptr3 + (T) * 64);                                \
    AF[4] = *(const bf16x8*)(aptr0 + (T) * 64 + 32);                           \
    AF[5] = *(const bf16x8*)(aptr1 + (T) * 64 + 32);                           \
    AF[6] = *(const bf16x8*)(aptr2 + (T) * 64 + 32);                           \
    AF[7] = *(const bf16x8*)(aptr3 + (T) * 64 + 32);                           \
    } while (0)

#define COMPUTE(T, AF) do {                                                    \
    const unsigned char* B_cur = bufB + ((T) & 1) * 16384;                     \
    _Pragma("unroll")                                                          \
    for (int ks = 0; ks < 2; ++ks) {                                           \
        _Pragma("unroll")                                                      \
        for (int nf = 0; nf < 4; ++nf) {                                       \
            bf16x8 bfr = *(const bf16x8*)(B_cur + swz(wn * 64 + nf * 16 + lr, ks * 64 + lg * 16)); \
            _Pragma("unroll")                                                  \
            for (int mf = 0; mf < 4; ++mf)                                     \
                acc[mf][nf] = __builtin_amdgcn_mfma_f32_16x16x32_bf16(         \
                    bfr, AF[ks * 4 + mf], acc[mf][nf], 0, 0, 0);               \
        }                                                                      \
    } } while (0)

// iter body: FP holds B(T+1) (packed now), FN receives B(T+3),
// AFC = A(T) (consumed), AFN receives A(T+1). W1/W4 = exact vmcnt leaves.
#define KBODY(T, FP, FN, AFC, AFN, W1, W4) do {                                \
    if ((T) + 1 < KSTEPS) { WAITV(W1); SB(); PACK(FP); WRITE_PK((T) + 1); }    \
    SB();                                                                      \
    if ((T) + 1 < KSTEPS) LOAD_AF(AFN, (T) + 1);                               \
    if ((T) + 3 < KSTEPS) LOAD_B(FN, (T) + 3);                                 \
    SB();                                                                      \
    WAITV(W4); SB();                                                           \
    COMPUTE(T, AFC);                                                           \
    if ((T) + 1 < KSTEPS) {                                                    \
        asm volatile("s_waitcnt lgkmcnt(0)" ::: "memory"); SB();               \
        __builtin_amdgcn_s_barrier(); SB();                                    \
    } } while (0)

    f32x4 acc[4][4];
    #pragma unroll
    for (int mf = 0; mf < 4; ++mf)
        #pragma unroll
        for (int nf = 0; nf < 4; ++nf)
            acc[mf][nf] = (f32x4)0.f;

    // ---- prologue: B(0),B(1),af(0) issued; drain only B(0); stage buf0; B(2) ----
    LOAD_B(f0, 0);
    LOAD_B(f1, 1);
    LOAD_AF(afA, 0);
    SB();
    WAITV(24); SB();                       // drains f0, leaves B(1):16 + af(0):8
    PACK(f0); WRITE_PK(0);
    LOAD_B(f2, 2);                         // outstanding: 24 + 16 = 40
    asm volatile("s_waitcnt lgkmcnt(0)" ::: "memory"); SB();
    __builtin_amdgcn_s_barrier(); SB();

    KBODY(0, f1, f0, afA, afB, 24, 40);
    KBODY(1, f2, f1, afB, afA, 24, 40);
    KBODY(2, f0, f2, afA, afB, 24, 40);
    KBODY(3, f1, f0, afB, afA, 24, 40);
    KBODY(4, f2, f1, afA, afB, 24, 40);
    KBODY(5, f0, f2, afB, afA, 24, 24);    // B(8) skipped -> fewer in flight
    KBODY(6, f1, f0, afA, afB, 8, 8);
    KBODY(7, f2, f1, afB, afA, 0, 0);      // drain-out; no PACK/loads/barrier

    // ---- deterministic column-norm reduction (part[] in buf0 region) ----
    __syncthreads();
    float* part = (float*)bufB;                // [16][128] floats = 8KB
    #pragma unroll
    for (int i = 0; i < 4; ++i)
        part[tid + i * 512] = bsq[i];          // slot = kq*128+n, unique owner
    __syncthreads();
    if (tid < BN) {
        float s = 0.f;
        #pragma unroll
        for (int k = 0; k < 16; ++k)
            s += part[k * BN + tid];           // fixed order -> deterministic
        rn[tid] = rsqrtf(fmaxf(s, 1e-12f));
    }
    __syncthreads();

    // ---- epilogue: LDS-staged -> 512B-aligned full-sector non-temporal stores ----
    float* stag = (float*)bufB;                // 32 rows x 132 floats = 16.9KB
    #pragma unroll
    for (int rd = 0; rd < 8; ++rd) {
        if (wm == (rd >> 1)) {
            #pragma unroll
            for (int f = 0; f < 2; ++f) {
                const int mf = (rd & 1) * 2 + f;
                const int ml = f * 16 + lr;
                #pragma unroll
                for (int nf = 0; nf < 4; ++nf) {
                    const int nl = wn * 64 + nf * 16 + lg * 4;
                    const f32x4 rn4 = *(const f32x4*)(rn + nl);
                    f32x4 o;
                    #pragma unroll
                    for (int r = 0; r < 4; ++r)
                        o[r] = acc[mf][nf][r] * rn4[r];
                    *(f32x4*)(stag + ml * 132 + nl) = o;
                }
            }
        }
        __syncthreads();
        #pragma unroll
        for (int j = tid; j < 1024; j += 512) {
            const int m = j >> 5;
            const int n = (j & 31) * 4;
            if (N0 + n + 4 <= CC) {
                f32x4 o = *(const f32x4*)(stag + m * 132 + n);
                __builtin_nontemporal_store(o,
                    (f32x4*)(out + (size_t)(M0 + rd * 32 + m) * CC + N0 + n));
            }
        }
        __syncthreads();
    }
}

// ---------------- K3: margin fixup at label positions ----------------
__global__ __launch_bounds__(512) void k_fix(const int* __restrict__ lab,
                                             float* __restrict__ out) {
    const int b = threadIdx.x;
    const int c = lab[b];
    const size_t idx = (size_t)b * CC + c;
    float t = out[idx];
    t = fminf(fmaxf(t, -1.f), 1.f);
    float th = acosf(t) + MARGIN2;
    th = fminf(th, PI_F);              // min(t, t + (pi - stopgrad(t))) value-wise
    out[idx] = cosf(th);               // M3 == 0: no additive term
}

extern "C" void kernel_launch(void* const* d_in, const int* in_sizes, int n_in,
                              void* d_out, int out_size, void* d_ws, size_t ws_size,
                              hipStream_t stream) {
    const float* x   = (const float*)d_in[0];
    const float* W   = (const float*)d_in[1];
    const int*   lab = (const int*)d_in[2];
    float* out = (float*)d_out;

    unsigned short* xnb = (unsigned short*)d_ws;   // 512*512*2 = 512 KB scratch

    k_norm_x<<<dim3(BB / 4), dim3(256), 0, stream>>>(x, xnb);
    k_gemm<<<dim3(GRID), dim3(512), 0, stream>>>(xnb, W, out);
    k_fix<<<dim3(1), dim3(512), 0, stream>>>(lab, out);
}

// Round 11
// 121.903 us; speedup vs baseline: 1.7332x; 1.3538x over previous
//
#include <hip/hip_runtime.h>
#include <math.h>

#define BB 512       // batch rows (M)
#define DD 512       // depth (K)
#define CC 100000    // classes (N)
#define MARGIN2 0.5f
#define PI_F 3.14159265358979323846f

#define BM 128
#define BN 128
#define BK 64
#define KSTEPS (DD / BK)     // 8
#define NPAN 782             // ceil(100000/128), last panel 32 cols
#define GRID (4 * NPAN)      // 3128 = 8 * 391 exactly

typedef __bf16 bf16x8 __attribute__((ext_vector_type(8)));
typedef float f32x4 __attribute__((ext_vector_type(4)));

static __device__ __forceinline__ unsigned short f2bf(float f) {
    union { float f; unsigned u; } v; v.f = f;
    unsigned r = v.u + 0x7FFFu + ((v.u >> 16) & 1u);   // round-to-nearest-even
    return (unsigned short)(r >> 16);
}

// swizzled LDS byte offset for row-major [row][64 x bf16] tiles (row stride 128B)
static __device__ __forceinline__ int swz(int row, int kbyte) {
    return row * 128 + (kbyte ^ ((row & 7) << 4));
}

// async global->LDS, 16B per lane; LDS dest = wave-uniform base + lane*16 (HW rule)
static __device__ __forceinline__ void gll16(const unsigned char* g, unsigned char* l) {
    __builtin_amdgcn_global_load_lds(
        (const __attribute__((address_space(1))) void*)g,
        (__attribute__((address_space(3))) void*)l, 16, 0, 0);
}

// ---------------- K1: row-normalize x -> bf16, PRE-SWIZZLED A images ----------------
// Image layout for BM=128: img[(mb*8 + t)*16384 + swz(lrow, c8*16) + sub*8],
// mb = row>>7, lrow = row&127 -> gemm's linear global_load_lds reproduces the
// swizzled Ash layout exactly (m173 pattern).
__global__ __launch_bounds__(256) void k_norm_x(const float* __restrict__ x,
                                                unsigned char* __restrict__ img) {
    const int lane = threadIdx.x & 63;
    const int row  = blockIdx.x * 4 + (threadIdx.x >> 6);
    const float* xr = x + (size_t)row * DD;
    float4 v0 = *(const float4*)(xr + lane * 4);
    float4 v1 = *(const float4*)(xr + lane * 4 + 256);
    float s = v0.x*v0.x + v0.y*v0.y + v0.z*v0.z + v0.w*v0.w
            + v1.x*v1.x + v1.y*v1.y + v1.z*v1.z + v1.w*v1.w;
    #pragma unroll
    for (int m = 32; m; m >>= 1) s += __shfl_xor(s, m, 64);
    float rs = rsqrtf(fmaxf(s, 1e-12f));
    ushort4 o0, o1;
    o0.x = f2bf(v0.x * rs); o0.y = f2bf(v0.y * rs);
    o0.z = f2bf(v0.z * rs); o0.w = f2bf(v0.w * rs);
    o1.x = f2bf(v1.x * rs); o1.y = f2bf(v1.y * rs);
    o1.z = f2bf(v1.z * rs); o1.w = f2bf(v1.w * rs);

    const int mb   = row >> 7;            // which 128-row M block (0..3)
    const int lrow = row & 127;
    const int k0   = lane * 4;            // v0 covers k0..k0+3; v1 covers k0+256..
    const int t0   = k0 >> 6;             // 0..3 (v1 -> t0+4)
    const int c8   = (k0 >> 3) & 7;       // 16B chunk within 128B row
    const int sub  = (k0 >> 2) & 1;       // 8B half of the chunk
    const int base = (mb * 8 + t0) * 16384 + lrow * 128
                   + ((c8 * 16) ^ ((lrow & 7) << 4)) + sub * 8;
    *(ushort4*)(img + base)         = o0;
    *(ushort4*)(img + base + 65536) = o1;    // t0+4 image (4 * 16384)
}

// ---------------- K2: bf16 MFMA GEMM, 128x128 tile, 2 blocks/CU, R8 pipeline ----
// 256 threads / 4 waves of 64x64 (acc 4x4 frags). LDS 64.5KB -> 2 blocks/CU:
// two desynchronized barrier domains per CU overlap each other's stage/MFMA.
// Per iter: [gll A(t+1):4][MFMA t, setprio][PACK B(t+1) auto-vmcnt(4) + ds_write]
// [LOAD B(t+2):32][vmcnt(32) drains glls only][lgkmcnt(0)][s_barrier].
// B(t+2) rides through the barrier (T4); max 36 in flight (<63 FIFO).
#define ABUF 16384
#define LDSZ (2 * ABUF + 2 * 16384 + 512)   // 66048 -> 2 blocks/CU

__global__ __launch_bounds__(256, 2) void k_gemm(const unsigned char* __restrict__ img,
                                                 const float* __restrict__ W,
                                                 float* __restrict__ out) {
    __shared__ __align__(16) unsigned char LDS[LDSZ];
    unsigned char* bufA = LDS;                  // 2 x 16KB
    unsigned char* bufB = LDS + 2 * ABUF;       // 2 x 16KB
    float* rn = (float*)(LDS + 2 * ABUF + 32768);

    const int tid = threadIdx.x;
    const int bid = blockIdx.x;

    // bijective XCD swizzle: 3128 = 8*391; 4 mb-sharers of a W panel -> same XCD L2
    const int v  = (bid & 7) * 391 + (bid >> 3);
    const int mb = v & 3;
    const int nb = v >> 2;
    const int M0 = mb * BM;
    const int N0 = nb * BN;

    const int lane = tid & 63;
    const int wid  = tid >> 6;     // 0..3
    const int wm = wid >> 1;       // 0..1 -> 64 rows each
    const int wn = wid & 1;        // 0..1 -> 64 cols each
    const int lr = lane & 15;
    const int lg = lane >> 4;

    // ---- B staging tasks: 8 per thread; s = kq*128 + n (bijective, also part[] slot) ----
    int b_go[8], b_ld[8];
    #pragma unroll
    for (int i = 0; i < 8; ++i) {
        int s  = tid + i * 256;
        int n  = s & 127;
        int kq = s >> 7;                       // 0..15, quad of k
        int col = N0 + n;
        col = col < CC ? col : CC - 1;         // tail-panel clamp (dead cols)
        b_go[i] = kq * 4 * CC + col;
        b_ld[i] = n * 128 + ((kq * 8) ^ ((n & 7) << 4));
    }

    const unsigned char* imgA = img + mb * (8 * ABUF);
    const int lds_u = wid * 4096;              // wave-uniform part of linear offset

    float    f0[8][4], f1[8][4];               // B in flight, 2-deep rotation
    unsigned pk[16];
    float    bsq[8] = {0.f, 0.f, 0.f, 0.f, 0.f, 0.f, 0.f, 0.f};

#define WAITV_(N) asm volatile("s_waitcnt vmcnt(" #N ")" ::: "memory")
#define WAITV(N) WAITV_(N)
#define SB() __builtin_amdgcn_sched_barrier(0)

#define LOAD_B(FR, T) do {                                                     \
    _Pragma("unroll")                                                          \
    for (int i = 0; i < 8; ++i) {                                              \
        const float* p = W + b_go[i] + (size_t)(T) * (BK * CC);                \
        FR[i][0] = p[0];      FR[i][1] = p[CC];                                \
        FR[i][2] = p[2 * CC]; FR[i][3] = p[3 * CC];                            \
    } } while (0)

#define PACK(FR) do {                                                          \
    _Pragma("unroll")                                                          \
    for (int i = 0; i < 8; ++i) {                                              \
        bsq[i] += FR[i][0] * FR[i][0] + FR[i][1] * FR[i][1]                    \
                + FR[i][2] * FR[i][2] + FR[i][3] * FR[i][3];                   \
        asm("v_cvt_pk_bf16_f32 %0, %1, %2" : "=v"(pk[2*i])   : "v"(FR[i][0]), "v"(FR[i][1])); \
        asm("v_cvt_pk_bf16_f32 %0, %1, %2" : "=v"(pk[2*i+1]) : "v"(FR[i][2]), "v"(FR[i][3])); \
    } } while (0)

#define WRITE_PK(T) do {                                                       \
    unsigned char* dst = bufB + ((T) & 1) * 16384;                             \
    _Pragma("unroll")                                                          \
    for (int i = 0; i < 8; ++i) {                                              \
        uint2 w; w.x = pk[2*i]; w.y = pk[2*i+1];                               \
        *(uint2*)(dst + b_ld[i]) = w;                                          \
    } } while (0)

#define GLL_A(T) do {                                                          \
    unsigned char* A_nxt = bufA + ((T) & 1) * ABUF;                            \
    const unsigned char* gsrc = imgA + (T) * ABUF;                             \
    _Pragma("unroll")                                                          \
    for (int i = 0; i < 4; ++i)                                                \
        gll16(gsrc + lds_u + i * 1024 + lane * 16, A_nxt + lds_u + i * 1024);  \
    } while (0)

#define COMPUTE(T) do {                                                        \
    const unsigned char* A_cur = bufA + ((T) & 1) * ABUF;                      \
    const unsigned char* B_cur = bufB + ((T) & 1) * 16384;                     \
    __builtin_amdgcn_s_setprio(1);                                             \
    _Pragma("unroll")                                                          \
    for (int ks = 0; ks < 2; ++ks) {                                           \
        bf16x8 af[4];                                                          \
        _Pragma("unroll")                                                      \
        for (int mf = 0; mf < 4; ++mf)                                         \
            af[mf] = *(const bf16x8*)(A_cur + swz(wm * 64 + mf * 16 + lr, ks * 64 + lg * 16)); \
        _Pragma("unroll")                                                      \
        for (int nf = 0; nf < 4; ++nf) {                                       \
            bf16x8 bfr = *(const bf16x8*)(B_cur + swz(wn * 64 + nf * 16 + lr, ks * 64 + lg * 16)); \
            _Pragma("unroll")                                                  \
            for (int mf = 0; mf < 4; ++mf)                                     \
                acc[mf][nf] = __builtin_amdgcn_mfma_f32_16x16x32_bf16(         \
                    bfr, af[mf], acc[mf][nf], 0, 0, 0);                        \
        }                                                                      \
    }                                                                          \
    __builtin_amdgcn_s_setprio(0);                                             \
    } while (0)

// iter body: FP holds B(T+1) (packed now), FN receives B(T+2)
#define KBODY(T, FP, FN) do {                                                  \
    if ((T) + 1 < KSTEPS) GLL_A((T) + 1);                                      \
    SB();                                                                      \
    COMPUTE(T);                                                                \
    SB();                                                                      \
    if ((T) + 1 < KSTEPS) { PACK(FP); WRITE_PK((T) + 1); }                     \
    if ((T) + 2 < KSTEPS) LOAD_B(FN, (T) + 2);                                 \
    SB();                                                                      \
    if ((T) + 1 < KSTEPS) {                                                    \
        if ((T) + 2 < KSTEPS) { WAITV(32); } else { WAITV(0); }                \
        SB();                                                                  \
        asm volatile("s_waitcnt lgkmcnt(0)" ::: "memory"); SB();               \
        __builtin_amdgcn_s_barrier(); SB();                                    \
    } } while (0)

    f32x4 acc[4][4];
    #pragma unroll
    for (int mf = 0; mf < 4; ++mf)
        #pragma unroll
        for (int nf = 0; nf < 4; ++nf)
            acc[mf][nf] = (f32x4)0.f;

    // ---- prologue: B(0):32 + gll(0):4; pack B(0) (vmcnt(4)); B(1):32; drain glls ----
    LOAD_B(f0, 0);
    GLL_A(0);
    SB();
    PACK(f0); WRITE_PK(0);                 // auto counted wait: drains B(0), keeps glls
    LOAD_B(f1, 1);                         // outstanding: gll(0):4 + B(1):32 = 36
    SB();
    WAITV(32); SB();                       // drain gll(0); B(1) rides through barrier
    asm volatile("s_waitcnt lgkmcnt(0)" ::: "memory"); SB();
    __builtin_amdgcn_s_barrier(); SB();

    KBODY(0, f1, f0);
    KBODY(1, f0, f1);
    KBODY(2, f1, f0);
    KBODY(3, f0, f1);
    KBODY(4, f1, f0);
    KBODY(5, f0, f1);
    KBODY(6, f1, f0);
    KBODY(7, f0, f1);

    // ---- deterministic column-norm reduction (reuse bufB) ----
    __syncthreads();
    float* part = (float*)bufB;                // [16][128] floats = 8KB
    #pragma unroll
    for (int i = 0; i < 8; ++i)
        part[tid + i * 256] = bsq[i];          // slot = kq*128+n, unique owner
    __syncthreads();
    if (tid < BN) {
        float s = 0.f;
        #pragma unroll
        for (int k = 0; k < 16; ++k)
            s += part[k * BN + tid];           // fixed order -> deterministic
        rn[tid] = rsqrtf(fmaxf(s, 1e-12f));
    }
    __syncthreads();

    // ---- epilogue: LDS-staged -> 512B-aligned full-sector non-temporal stores ----
    float* stag = (float*)bufA;                // 32 rows x 132 floats = 16.9KB
    #pragma unroll
    for (int rd = 0; rd < 4; ++rd) {
        if (wm == (rd >> 1)) {
            #pragma unroll
            for (int f = 0; f < 2; ++f) {
                const int mf = (rd & 1) * 2 + f;
                const int ml = f * 16 + lr;
                #pragma unroll
                for (int nf = 0; nf < 4; ++nf) {
                    const int nl = wn * 64 + nf * 16 + lg * 4;
                    const f32x4 rn4 = *(const f32x4*)(rn + nl);
                    f32x4 o;
                    #pragma unroll
                    for (int r = 0; r < 4; ++r)
                        o[r] = acc[mf][nf][r] * rn4[r];
                    *(f32x4*)(stag + ml * 132 + nl) = o;
                }
            }
        }
        __syncthreads();
        #pragma unroll
        for (int j = tid; j < 1024; j += 256) {
            const int m = j >> 5;
            const int n = (j & 31) * 4;
            if (N0 + n + 4 <= CC) {
                f32x4 o = *(const f32x4*)(stag + m * 132 + n);
                __builtin_nontemporal_store(o,
                    (f32x4*)(out + (size_t)(M0 + rd * 32 + m) * CC + N0 + n));
            }
        }
        __syncthreads();
    }
}

// ---------------- K3: margin fixup at label positions ----------------
__global__ __launch_bounds__(512) void k_fix(const int* __restrict__ lab,
                                             float* __restrict__ out) {
    const int b = threadIdx.x;
    const int c = lab[b];
    const size_t idx = (size_t)b * CC + c;
    float t = out[idx];
    t = fminf(fmaxf(t, -1.f), 1.f);
    float th = acosf(t) + MARGIN2;
    th = fminf(th, PI_F);              // min(t, t + (pi - stopgrad(t))) value-wise
    out[idx] = cosf(th);               // M3 == 0: no additive term
}

extern "C" void kernel_launch(void* const* d_in, const int* in_sizes, int n_in,
                              void* d_out, int out_size, void* d_ws, size_t ws_size,
                              hipStream_t stream) {
    const float* x   = (const float*)d_in[0];
    const float* W   = (const float*)d_in[1];
    const int*   lab = (const int*)d_in[2];
    float* out = (float*)d_out;

    unsigned char* img = (unsigned char*)d_ws;   // 512KB pre-swizzled xn images

    k_norm_x<<<dim3(BB / 4), dim3(256), 0, stream>>>(x, img);
    k_gemm<<<dim3(GRID), dim3(256), 0, stream>>>(img, W, out);
    k_fix<<<dim3(1), dim3(512), 0, stream>>>(lab, out);
}

// Round 12
// 110.274 us; speedup vs baseline: 1.9160x; 1.1055x over previous
//
#include <hip/hip_runtime.h>
#include <math.h>

#define BB 512       // batch rows (M)
#define DD 512       // depth (K)
#define CC 100000    // classes (N)
#define MARGIN2 0.5f
#define PI_F 3.14159265358979323846f

#define BM 128
#define BN 128
#define BK 64
#define KSTEPS (DD / BK)     // 8
#define NPAN 782             // ceil(100000/128), last panel 32 cols
#define GRID (4 * NPAN)      // 3128 = 8 * 391 exactly

typedef __bf16 bf16x8 __attribute__((ext_vector_type(8)));
typedef float f32x4 __attribute__((ext_vector_type(4)));

static __device__ __forceinline__ unsigned short f2bf(float f) {
    union { float f; unsigned u; } v; v.f = f;
    unsigned r = v.u + 0x7FFFu + ((v.u >> 16) & 1u);   // round-to-nearest-even
    return (unsigned short)(r >> 16);
}

// swizzled LDS byte offset for row-major [row][64 x bf16] tiles (row stride 128B)
static __device__ __forceinline__ int swz(int row, int kbyte) {
    return row * 128 + (kbyte ^ ((row & 7) << 4));
}

// async global->LDS, 16B per lane; LDS dest = wave-uniform base + lane*16 (HW rule)
static __device__ __forceinline__ void gll16(const unsigned char* g, unsigned char* l) {
    __builtin_amdgcn_global_load_lds(
        (const __attribute__((address_space(1))) void*)g,
        (__attribute__((address_space(3))) void*)l, 16, 0, 0);
}

// ---------------- K1: row-normalize x -> bf16, PRE-SWIZZLED A images ----------------
// Image layout for BM=128: img[(mb*8 + t)*16384 + swz(lrow, c8*16) + sub*8],
// mb = row>>7, lrow = row&127 -> gemm's linear global_load_lds reproduces the
// swizzled Ash layout exactly (m173 pattern).
__global__ __launch_bounds__(256) void k_norm_x(const float* __restrict__ x,
                                                unsigned char* __restrict__ img) {
    const int lane = threadIdx.x & 63;
    const int row  = blockIdx.x * 4 + (threadIdx.x >> 6);
    const float* xr = x + (size_t)row * DD;
    float4 v0 = *(const float4*)(xr + lane * 4);
    float4 v1 = *(const float4*)(xr + lane * 4 + 256);
    float s = v0.x*v0.x + v0.y*v0.y + v0.z*v0.z + v0.w*v0.w
            + v1.x*v1.x + v1.y*v1.y + v1.z*v1.z + v1.w*v1.w;
    #pragma unroll
    for (int m = 32; m; m >>= 1) s += __shfl_xor(s, m, 64);
    float rs = rsqrtf(fmaxf(s, 1e-12f));
    ushort4 o0, o1;
    o0.x = f2bf(v0.x * rs); o0.y = f2bf(v0.y * rs);
    o0.z = f2bf(v0.z * rs); o0.w = f2bf(v0.w * rs);
    o1.x = f2bf(v1.x * rs); o1.y = f2bf(v1.y * rs);
    o1.z = f2bf(v1.z * rs); o1.w = f2bf(v1.w * rs);

    const int mb   = row >> 7;            // which 128-row M block (0..3)
    const int lrow = row & 127;
    const int k0   = lane * 4;            // v0 covers k0..k0+3; v1 covers k0+256..
    const int t0   = k0 >> 6;             // 0..3 (v1 -> t0+4)
    const int c8   = (k0 >> 3) & 7;       // 16B chunk within 128B row
    const int sub  = (k0 >> 2) & 1;       // 8B half of the chunk
    const int base = (mb * 8 + t0) * 16384 + lrow * 128
                   + ((c8 * 16) ^ ((lrow & 7) << 4)) + sub * 8;
    *(ushort4*)(img + base)         = o0;
    *(ushort4*)(img + base + 65536) = o1;    // t0+4 image (4 * 16384)
}

// ---------------- K2: bf16 MFMA GEMM, 128x128 tile, 4 waves/SIMD pipeline ----
// 512 threads / 8 waves of 64x32 (acc = 8 frags = 32 AGPR). Combined regs
// ~124 <= 128 -> 4 waves/SIMD; LDS 64.5KB -> 2 blocks/CU -> 16 waves/CU.
// R8 pipeline: per iter [gll A(t+1):2/wave][MFMA t, setprio][PACK+write B(t+1),
// auto-counted vmcnt][LOAD B(t+2):16][vmcnt(16)][lgkmcnt(0)][s_barrier].
// B(t+2) rides through the barrier (T4); max 34 in flight (<63 FIFO).
#define ABUF 16384
#define LDSZ (2 * ABUF + 2 * 16384 + 512)   // 66048 -> 2 blocks/CU

__global__ __launch_bounds__(512, 4) void k_gemm(const unsigned char* __restrict__ img,
                                                 const float* __restrict__ W,
                                                 float* __restrict__ out) {
    __shared__ __align__(16) unsigned char LDS[LDSZ];
    unsigned char* bufA = LDS;                  // 2 x 16KB
    unsigned char* bufB = LDS + 2 * ABUF;       // 2 x 16KB
    float* rn = (float*)(LDS + 2 * ABUF + 32768);

    const int tid = threadIdx.x;
    const int bid = blockIdx.x;

    // bijective XCD swizzle: 3128 = 8*391; 4 mb-sharers of a W panel -> same XCD L2
    const int v  = (bid & 7) * 391 + (bid >> 3);
    const int mb = v & 3;
    const int nb = v >> 2;
    const int M0 = mb * BM;
    const int N0 = nb * BN;

    const int lane = tid & 63;
    const int wid  = tid >> 6;     // 0..7
    const int wm = wid >> 2;       // 0..1 -> 64 rows each
    const int wn = wid & 3;        // 0..3 -> 32 cols each
    const int lr = lane & 15;
    const int lg = lane >> 4;

    // ---- B staging tasks: 4 per thread; s = kq*128 + n (bijective, also part[] slot) ----
    int b_go[4], b_ld[4];
    #pragma unroll
    for (int i = 0; i < 4; ++i) {
        int s  = tid + i * 512;
        int n  = s & 127;
        int kq = s >> 7;                       // 0..15, quad of k
        int col = N0 + n;
        col = col < CC ? col : CC - 1;         // tail-panel clamp (dead cols)
        b_go[i] = kq * 4 * CC + col;
        b_ld[i] = n * 128 + ((kq * 8) ^ ((n & 7) << 4));
    }

    const unsigned char* imgA = img + mb * (8 * ABUF);
    const int lds_u = wid * 2048;              // wave-uniform part of linear offset

    float f0[4][4], f1[4][4];                  // B in flight, 2-deep rotation
    float bsq[4] = {0.f, 0.f, 0.f, 0.f};

#define WAITV_(N) asm volatile("s_waitcnt vmcnt(" #N ")" ::: "memory")
#define WAITV(N) WAITV_(N)
#define SB() __builtin_amdgcn_sched_barrier(0)

#define LOAD_B(FR, T) do {                                                     \
    _Pragma("unroll")                                                          \
    for (int i = 0; i < 4; ++i) {                                              \
        const float* p = W + b_go[i] + (size_t)(T) * (BK * CC);                \
        FR[i][0] = p[0];      FR[i][1] = p[CC];                                \
        FR[i][2] = p[2 * CC]; FR[i][3] = p[3 * CC];                            \
    } } while (0)

// pack + write immediately (no pk array - register budget)
#define PACK_WRITE(FR, T) do {                                                 \
    unsigned char* dst = bufB + ((T) & 1) * 16384;                             \
    _Pragma("unroll")                                                          \
    for (int i = 0; i < 4; ++i) {                                              \
        bsq[i] += FR[i][0] * FR[i][0] + FR[i][1] * FR[i][1]                    \
                + FR[i][2] * FR[i][2] + FR[i][3] * FR[i][3];                   \
        unsigned w0, w1;                                                       \
        asm("v_cvt_pk_bf16_f32 %0, %1, %2" : "=v"(w0) : "v"(FR[i][0]), "v"(FR[i][1])); \
        asm("v_cvt_pk_bf16_f32 %0, %1, %2" : "=v"(w1) : "v"(FR[i][2]), "v"(FR[i][3])); \
        uint2 w; w.x = w0; w.y = w1;                                           \
        *(uint2*)(dst + b_ld[i]) = w;                                          \
    } } while (0)

#define GLL_A(T) do {                                                          \
    unsigned char* A_nxt = bufA + ((T) & 1) * ABUF;                            \
    const unsigned char* gsrc = imgA + (T) * ABUF;                             \
    gll16(gsrc + lds_u + lane * 16, A_nxt + lds_u);                            \
    gll16(gsrc + lds_u + 1024 + lane * 16, A_nxt + lds_u + 1024);              \
    } while (0)

#define COMPUTE(T) do {                                                        \
    const unsigned char* A_cur = bufA + ((T) & 1) * ABUF;                      \
    const unsigned char* B_cur = bufB + ((T) & 1) * 16384;                     \
    __builtin_amdgcn_s_setprio(1);                                             \
    _Pragma("unroll")                                                          \
    for (int ks = 0; ks < 2; ++ks) {                                           \
        bf16x8 af[4], bfr[2];                                                  \
        _Pragma("unroll")                                                      \
        for (int mf = 0; mf < 4; ++mf)                                         \
            af[mf] = *(const bf16x8*)(A_cur + swz(wm * 64 + mf * 16 + lr, ks * 64 + lg * 16)); \
        _Pragma("unroll")                                                      \
        for (int nf = 0; nf < 2; ++nf)                                         \
            bfr[nf] = *(const bf16x8*)(B_cur + swz(wn * 32 + nf * 16 + lr, ks * 64 + lg * 16)); \
        _Pragma("unroll")                                                      \
        for (int mf = 0; mf < 4; ++mf)                                         \
            _Pragma("unroll")                                                  \
            for (int nf = 0; nf < 2; ++nf)                                     \
                acc[mf][nf] = __builtin_amdgcn_mfma_f32_16x16x32_bf16(         \
                    bfr[nf], af[mf], acc[mf][nf], 0, 0, 0);                    \
    }                                                                          \
    __builtin_amdgcn_s_setprio(0);                                             \
    } while (0)

// iter body: FP holds B(T+1) (packed now), FN receives B(T+2)
#define KBODY(T, FP, FN) do {                                                  \
    if ((T) + 1 < KSTEPS) GLL_A((T) + 1);                                      \
    SB();                                                                      \
    COMPUTE(T);                                                                \
    SB();                                                                      \
    if ((T) + 1 < KSTEPS) PACK_WRITE(FP, (T) + 1);                             \
    if ((T) + 2 < KSTEPS) LOAD_B(FN, (T) + 2);                                 \
    SB();                                                                      \
    if ((T) + 1 < KSTEPS) {                                                    \
        if ((T) + 2 < KSTEPS) { WAITV(16); } else { WAITV(0); }                \
        SB();                                                                  \
        asm volatile("s_waitcnt lgkmcnt(0)" ::: "memory"); SB();               \
        __builtin_amdgcn_s_barrier(); SB();                                    \
    } } while (0)

    f32x4 acc[4][2];
    #pragma unroll
    for (int mf = 0; mf < 4; ++mf)
        #pragma unroll
        for (int nf = 0; nf < 2; ++nf)
            acc[mf][nf] = (f32x4)0.f;

    // ---- prologue: B(0):16 + gll(0):2; pack B(0) (auto-counted); B(1):16; drain glls ----
    LOAD_B(f0, 0);
    GLL_A(0);
    SB();
    PACK_WRITE(f0, 0);                     // auto wait drains B(0), keeps glls
    LOAD_B(f1, 1);                         // outstanding: gll(0):2 + B(1):16 = 18
    SB();
    WAITV(16); SB();                       // drain gll(0); B(1) rides through barrier
    asm volatile("s_waitcnt lgkmcnt(0)" ::: "memory"); SB();
    __builtin_amdgcn_s_barrier(); SB();

    KBODY(0, f1, f0);
    KBODY(1, f0, f1);
    KBODY(2, f1, f0);
    KBODY(3, f0, f1);
    KBODY(4, f1, f0);
    KBODY(5, f0, f1);
    KBODY(6, f1, f0);
    KBODY(7, f0, f1);

    // ---- deterministic column-norm reduction (reuse bufB) ----
    __syncthreads();
    float* part = (float*)bufB;                // [16][128] floats = 8KB
    #pragma unroll
    for (int i = 0; i < 4; ++i)
        part[tid + i * 512] = bsq[i];          // slot = kq*128+n, unique owner
    __syncthreads();
    if (tid < BN) {
        float s = 0.f;
        #pragma unroll
        for (int k = 0; k < 16; ++k)
            s += part[k * BN + tid];           // fixed order -> deterministic
        rn[tid] = rsqrtf(fmaxf(s, 1e-12f));
    }
    __syncthreads();

    // ---- epilogue: LDS-staged -> 512B-aligned full-sector non-temporal stores ----
    float* stag = (float*)bufA;                // 32 rows x 132 floats = 16.9KB
    #pragma unroll
    for (int rd = 0; rd < 4; ++rd) {
        if (wm == (rd >> 1)) {
            #pragma unroll
            for (int f = 0; f < 2; ++f) {
                const int mf = (rd & 1) * 2 + f;
                const int ml = f * 16 + lr;
                #pragma unroll
                for (int nf = 0; nf < 2; ++nf) {
                    const int nl = wn * 32 + nf * 16 + lg * 4;
                    const f32x4 rn4 = *(const f32x4*)(rn + nl);
                    f32x4 o;
                    #pragma unroll
                    for (int r = 0; r < 4; ++r)
                        o[r] = acc[mf][nf][r] * rn4[r];
                    *(f32x4*)(stag + ml * 132 + nl) = o;
                }
            }
        }
        __syncthreads();
        #pragma unroll
        for (int j = tid; j < 1024; j += 512) {
            const int m = j >> 5;
            const int n = (j & 31) * 4;
            if (N0 + n + 4 <= CC) {
                f32x4 o = *(const f32x4*)(stag + m * 132 + n);
                __builtin_nontemporal_store(o,
                    (f32x4*)(out + (size_t)(M0 + rd * 32 + m) * CC + N0 + n));
            }
        }
        __syncthreads();
    }
}

// ---------------- K3: margin fixup at label positions ----------------
__global__ __launch_bounds__(512) void k_fix(const int* __restrict__ lab,
                                             float* __restrict__ out) {
    const int b = threadIdx.x;
    const int c = lab[b];
    const size_t idx = (size_t)b * CC + c;
    float t = out[idx];
    t = fminf(fmaxf(t, -1.f), 1.f);
    float th = acosf(t) + MARGIN2;
    th = fminf(th, PI_F);              // min(t, t + (pi - stopgrad(t))) value-wise
    out[idx] = cosf(th);               // M3 == 0: no additive term
}

extern "C" void kernel_launch(void* const* d_in, const int* in_sizes, int n_in,
                              void* d_out, int out_size, void* d_ws, size_t ws_size,
                              hipStream_t stream) {
    const float* x   = (const float*)d_in[0];
    const float* W   = (const float*)d_in[1];
    const int*   lab = (const int*)d_in[2];
    float* out = (float*)d_out;

    unsigned char* img = (unsigned char*)d_ws;   // 512KB pre-swizzled xn images

    k_norm_x<<<dim3(BB / 4), dim3(256), 0, stream>>>(x, img);
    k_gemm<<<dim3(GRID), dim3(512), 0, stream>>>(img, W, out);
    k_fix<<<dim3(1), dim3(512), 0, stream>>>(lab, out);
}